// Round 1
// baseline (164.555 us; speedup 1.0000x reference)
//
#include <hip/hip_runtime.h>
#include <math.h>

// D = 8192, BATCH = 4096
// out[b, j] = x[b] * w_col[j]
// w_col[j]  = s1[0] * s2[j] * FWHT(g_tilde)[j]
// g_tilde[i] = g_mu[i] + softplus(g_rho[i]) * epsilon[i]
//
// Derivation: W = s1[:,None] * H @ (g_tilde[:,None] * (H @ diag(s2))).
// w_col = first D elems of row-major flatten = W[0,:]. Row 0 of the Sylvester
// Hadamard is all +1 and H is symmetric, so W[0,j] = s1[0]*s2[j]*(H g_tilde)[j].

#define WHVI_D 8192
#define WHVI_BATCH 4096

__global__ __launch_bounds__(1024) void whvi_fwht_wcol(
    const float* __restrict__ s1, const float* __restrict__ s2,
    const float* __restrict__ g_mu, const float* __restrict__ g_rho,
    const float* __restrict__ eps, float* __restrict__ w) {
  __shared__ float s[WHVI_D];
  const int tid = threadIdx.x;

  // g_tilde = g_mu + softplus(g_rho) * epsilon  (numerically stable softplus)
  for (int i = tid; i < WHVI_D; i += 1024) {
    float r = g_rho[i];
    float sp = fmaxf(r, 0.0f) + log1pf(expf(-fabsf(r)));
    s[i] = g_mu[i] + sp * eps[i];
  }

  // 13-stage in-place FWHT over LDS. h=1..4096; each stage 4096 butterflies,
  // 4 per thread. Stride-2 LDS access at small h is only 2-way aliasing (free).
  for (int h = 1; h < WHVI_D; h <<= 1) {
    __syncthreads();
    for (int p = tid; p < WHVI_D / 2; p += 1024) {
      int k = p & (h - 1);
      int i = ((p - k) << 1) + k;  // (p/h)*2h + k
      float a = s[i];
      float b = s[i + h];
      s[i]     = a + b;
      s[i + h] = a - b;
    }
  }
  __syncthreads();

  const float s10 = s1[0];
  for (int j = tid; j < WHVI_D; j += 1024) {
    w[j] = s10 * s2[j] * s[j];
  }
}

// Outer product: out[b*D + j] = x[b] * w[j], float4-vectorized.
// Each consecutive 2048 threads share one b (uniform per wave64).
__global__ __launch_bounds__(256) void whvi_outer(
    const float* __restrict__ x, const float* __restrict__ w,
    float* __restrict__ out) {
  const int idx = blockIdx.x * blockDim.x + threadIdx.x;  // float4 index
  const int b  = idx >> 11;            // D/4 = 2048 float4 per row
  const int j4 = idx & 2047;
  const float xb = x[b];
  const float4 w4 = ((const float4*)w)[j4];
  float4 o;
  o.x = xb * w4.x;
  o.y = xb * w4.y;
  o.z = xb * w4.z;
  o.w = xb * w4.w;
  ((float4*)out)[idx] = o;
}

extern "C" void kernel_launch(void* const* d_in, const int* in_sizes, int n_in,
                              void* d_out, int out_size, void* d_ws, size_t ws_size,
                              hipStream_t stream) {
  const float* x     = (const float*)d_in[0];  // (4096,1)
  const float* s1    = (const float*)d_in[1];  // (8192,)
  const float* s2    = (const float*)d_in[2];  // (8192,)
  const float* g_mu  = (const float*)d_in[3];  // (8192,)
  const float* g_rho = (const float*)d_in[4];  // (8192,)
  const float* eps   = (const float*)d_in[5];  // (8192,)
  float* out = (float*)d_out;                  // (4096, 8192)
  float* w   = (float*)d_ws;                   // 8192 floats scratch

  whvi_fwht_wcol<<<1, 1024, 0, stream>>>(s1, s2, g_mu, g_rho, eps, w);

  const int n4 = (WHVI_BATCH * WHVI_D) / 4;    // 8,388,608 float4 stores
  whvi_outer<<<n4 / 256, 256, 0, stream>>>(x, w, out);
}

// Round 3
// 162.629 us; speedup vs baseline: 1.0118x; 1.0118x over previous
//
#include <hip/hip_runtime.h>
#include <math.h>

// D = 8192, BATCH = 4096
// out[b, j] = x[b] * w_col[j]
// w_col[j]  = s1[0] * s2[j] * FWHT(g_tilde)[j]
// g_tilde[i] = g_mu[i] + softplus(g_rho[i]) * epsilon[i]
//
// Derivation: W = s1[:,None] * H @ (g_tilde[:,None] * (H @ diag(s2))).
// w_col = first D elems of row-major flatten = W[0,:]. Row 0 of the Sylvester
// Hadamard is all +1 and H is symmetric, so W[0,j] = s1[0]*s2[j]*(H g_tilde)[j].

#define WHVI_D 8192
#define WHVI_BATCH 4096

// Native clang vector type — __builtin_nontemporal_store requires this
// (HIP's float4 is a class and is rejected).
typedef float v4f __attribute__((ext_vector_type(4)));

__global__ __launch_bounds__(1024) void whvi_fwht_wcol(
    const float* __restrict__ s1, const float* __restrict__ s2,
    const float* __restrict__ g_mu, const float* __restrict__ g_rho,
    const float* __restrict__ eps, float* __restrict__ w) {
  __shared__ float s[WHVI_D];
  const int tid = threadIdx.x;

  // g_tilde = g_mu + softplus(g_rho) * epsilon, float4-vectorized loads.
  {
    const float4* mu4 = (const float4*)g_mu;
    const float4* rh4 = (const float4*)g_rho;
    const float4* ep4 = (const float4*)eps;
    for (int i = tid; i < WHVI_D / 4; i += 1024) {
      float4 m = mu4[i], r = rh4[i], e = ep4[i];
      float4 g;
      g.x = m.x + (fmaxf(r.x, 0.0f) + log1pf(expf(-fabsf(r.x)))) * e.x;
      g.y = m.y + (fmaxf(r.y, 0.0f) + log1pf(expf(-fabsf(r.y)))) * e.y;
      g.z = m.z + (fmaxf(r.z, 0.0f) + log1pf(expf(-fabsf(r.z)))) * e.z;
      g.w = m.w + (fmaxf(r.w, 0.0f) + log1pf(expf(-fabsf(r.w)))) * e.w;
      ((float4*)s)[i] = g;
    }
  }

  // 13-stage in-place FWHT over LDS. Worst LDS aliasing is 2-way (free).
  for (int h = 1; h < WHVI_D; h <<= 1) {
    __syncthreads();
    for (int p = tid; p < WHVI_D / 2; p += 1024) {
      int k = p & (h - 1);
      int i = ((p - k) << 1) + k;  // (p/h)*2h + k
      float a = s[i];
      float b = s[i + h];
      s[i]     = a + b;
      s[i + h] = a - b;
    }
  }
  __syncthreads();

  const float s10 = s1[0];
  {
    const float4* s24 = (const float4*)s2;
    float4* w4 = (float4*)w;
    for (int i = tid; i < WHVI_D / 4; i += 1024) {
      float4 t = ((float4*)s)[i];
      float4 c = s24[i];
      float4 o;
      o.x = s10 * c.x * t.x;
      o.y = s10 * c.y * t.y;
      o.z = s10 * c.z * t.z;
      o.w = s10 * c.w * t.w;
      w4[i] = o;
    }
  }
}

// Outer product: one block per output row. 256 threads x 8 float4 each
// (stride-256 float4 = fully coalesced 16B/lane). x[b] loaded once per
// block (scalar-broadcast), w re-read from L1/L2 (32 KB, fully cached).
// Non-temporal stores: pure streaming output, no reuse.
__global__ __launch_bounds__(256) void whvi_outer(
    const float* __restrict__ x, const float* __restrict__ w,
    float* __restrict__ out) {
  const int b = blockIdx.x;
  const float xb = x[b];
  const v4f* __restrict__ w4 = (const v4f*)w;
  v4f* __restrict__ o4 = (v4f*)(out + (size_t)b * WHVI_D);

  v4f v[8];
  #pragma unroll
  for (int t = 0; t < 8; ++t) v[t] = w4[threadIdx.x + t * 256];
  #pragma unroll
  for (int t = 0; t < 8; ++t) {
    v4f r = xb * v[t];
    __builtin_nontemporal_store(r, &o4[threadIdx.x + t * 256]);
  }
}

extern "C" void kernel_launch(void* const* d_in, const int* in_sizes, int n_in,
                              void* d_out, int out_size, void* d_ws, size_t ws_size,
                              hipStream_t stream) {
  const float* x     = (const float*)d_in[0];  // (4096,1)
  const float* s1    = (const float*)d_in[1];  // (8192,)
  const float* s2    = (const float*)d_in[2];  // (8192,)
  const float* g_mu  = (const float*)d_in[3];  // (8192,)
  const float* g_rho = (const float*)d_in[4];  // (8192,)
  const float* eps   = (const float*)d_in[5];  // (8192,)
  float* out = (float*)d_out;                  // (4096, 8192)
  float* w   = (float*)d_ws;                   // 8192 floats scratch

  whvi_fwht_wcol<<<1, 1024, 0, stream>>>(s1, s2, g_mu, g_rho, eps, w);
  whvi_outer<<<WHVI_BATCH, 256, 0, stream>>>(x, w, out);
}

// Round 4
// 162.134 us; speedup vs baseline: 1.0149x; 1.0031x over previous
//
#include <hip/hip_runtime.h>
#include <math.h>

// D = 8192, BATCH = 4096
// out[b, j] = x[b] * w_col[j]
// w_col[j]  = s1[0] * s2[j] * FWHT(g_tilde)[j]
// g_tilde[i] = g_mu[i] + softplus(g_rho[i]) * epsilon[i]
//
// Derivation: W = s1[:,None] * H @ (g_tilde[:,None] * (H @ diag(s2))).
// w_col = first D elems of row-major flatten = W[0,:]. Row 0 of the Sylvester
// Hadamard is all +1 and H is symmetric, so W[0,j] = s1[0]*s2[j]*(H g_tilde)[j].
//
// Fully fused single launch: each block redundantly computes the 8192-pt FWHT
// in LDS (~1.4 us of LDS traffic — cheap), then streams 8 output rows with NT
// stores. 512 blocks x 1024 thr = 2 blocks/CU (64 KB LDS, 32 waves/CU).

#define WHVI_D 8192
#define WHVI_BATCH 4096
#define ROWS_PER_BLOCK 8   // 4096 / 512 blocks

typedef float v4f __attribute__((ext_vector_type(4)));

__global__ __launch_bounds__(1024) void whvi_fused(
    const float* __restrict__ x, const float* __restrict__ s1,
    const float* __restrict__ s2, const float* __restrict__ g_mu,
    const float* __restrict__ g_rho, const float* __restrict__ eps,
    float* __restrict__ out) {
  __shared__ float s[WHVI_D];
  const int tid = threadIdx.x;

  // g_tilde = g_mu + softplus(g_rho) * epsilon  (2 float4 per thread)
  {
    const float4* mu4 = (const float4*)g_mu;
    const float4* rh4 = (const float4*)g_rho;
    const float4* ep4 = (const float4*)eps;
    #pragma unroll
    for (int t = 0; t < 2; ++t) {
      int i = tid + t * 1024;
      float4 m = mu4[i], r = rh4[i], e = ep4[i];
      float4 g;
      g.x = m.x + (fmaxf(r.x, 0.0f) + log1pf(expf(-fabsf(r.x)))) * e.x;
      g.y = m.y + (fmaxf(r.y, 0.0f) + log1pf(expf(-fabsf(r.y)))) * e.y;
      g.z = m.z + (fmaxf(r.z, 0.0f) + log1pf(expf(-fabsf(r.z)))) * e.z;
      g.w = m.w + (fmaxf(r.w, 0.0f) + log1pf(expf(-fabsf(r.w)))) * e.w;
      ((float4*)s)[i] = g;
    }
  }

  // 13-stage in-place FWHT over LDS. Worst LDS aliasing is 2-way (free).
  for (int h = 1; h < WHVI_D; h <<= 1) {
    __syncthreads();
    #pragma unroll
    for (int t = 0; t < 4; ++t) {
      int p = tid + t * 1024;           // 4096 butterflies, 4 per thread
      int k = p & (h - 1);
      int i = ((p - k) << 1) + k;       // (p/h)*2h + k
      float a = s[i];
      float b = s[i + h];
      s[i]     = a + b;
      s[i + h] = a - b;
    }
  }
  __syncthreads();

  // Per-thread w fragments (2 float4 each): w = s1[0] * s2 * fwht(g_tilde)
  const float s10 = s1[0];
  const v4f* s24 = (const v4f*)s2;
  const v4f* sh4 = (const v4f*)s;
  v4f w0 = (s10 * s24[tid]) * sh4[tid];
  v4f w1 = (s10 * s24[tid + 1024]) * sh4[tid + 1024];

  // Stream 8 rows: out[row, :] = x[row] * w  (NT stores — pure streaming)
  const int row0 = blockIdx.x * ROWS_PER_BLOCK;
  #pragma unroll
  for (int r = 0; r < ROWS_PER_BLOCK; ++r) {
    const int row = row0 + r;
    const float xb = x[row];
    v4f* o4 = (v4f*)(out + (size_t)row * WHVI_D);
    __builtin_nontemporal_store(xb * w0, &o4[tid]);
    __builtin_nontemporal_store(xb * w1, &o4[tid + 1024]);
  }
}

extern "C" void kernel_launch(void* const* d_in, const int* in_sizes, int n_in,
                              void* d_out, int out_size, void* d_ws, size_t ws_size,
                              hipStream_t stream) {
  const float* x     = (const float*)d_in[0];  // (4096,1)
  const float* s1    = (const float*)d_in[1];  // (8192,)
  const float* s2    = (const float*)d_in[2];  // (8192,)
  const float* g_mu  = (const float*)d_in[3];  // (8192,)
  const float* g_rho = (const float*)d_in[4];  // (8192,)
  const float* eps   = (const float*)d_in[5];  // (8192,)
  float* out = (float*)d_out;                  // (4096, 8192)

  whvi_fused<<<WHVI_BATCH / ROWS_PER_BLOCK, 1024, 0, stream>>>(
      x, s1, s2, g_mu, g_rho, eps, out);
}